// Round 2
// baseline (374.381 us; speedup 1.0000x reference)
//
#include <hip/hip_runtime.h>

typedef __attribute__((ext_vector_type(4))) float f32x4;
typedef __attribute__((ext_vector_type(8))) short bf16x8;
typedef __attribute__((ext_vector_type(4))) unsigned short u16x4;

static __device__ __forceinline__ unsigned short f2bf(float f) {
    union { float f; unsigned int u; } a; a.f = f;
    unsigned int u = a.u;
    unsigned int r = (u + 0x7FFFu + ((u >> 16) & 1u)) >> 16;
    return (unsigned short)r;
}
static __device__ __forceinline__ float bf2f(unsigned short h) {
    union { unsigned int u; float f; } a; a.u = ((unsigned int)h) << 16;
    return a.f;
}

// ---------------- convert x (fp32 -> bf16), vectorized ----------------
__global__ __launch_bounds__(256) void cvt_f32_bf16(const float* __restrict__ in,
                                                    unsigned short* __restrict__ out) {
    long long i = ((long long)blockIdx.x * 256 + threadIdx.x) * 4;
    float4 f = *(const float4*)(in + i);
    u16x4 u;
    u[0] = f2bf(f.x); u[1] = f2bf(f.y); u[2] = f2bf(f.z); u[3] = f2bf(f.w);
    *(u16x4*)(out + i) = u;
}

// ---------------- transpose W [1024][1024] f32 -> Wt [1024][1024] bf16 ----------------
__global__ __launch_bounds__(256) void transpose_w(const float* __restrict__ W0,
                                                   const float* __restrict__ W1,
                                                   const float* __restrict__ W2,
                                                   unsigned short* __restrict__ Wt) {
    __shared__ float t[32][33];
    int mat = blockIdx.z;
    const float* W = (mat == 0) ? W0 : (mat == 1) ? W1 : W2;
    unsigned short* out = Wt + (long long)mat * 1024 * 1024;
    int n0 = blockIdx.x * 32, k0 = blockIdx.y * 32;
    int tx = threadIdx.x, ty = threadIdx.y;   // 32 x 8
#pragma unroll
    for (int q = 0; q < 4; ++q)
        t[ty + 8 * q][tx] = W[(long long)(k0 + ty + 8 * q) * 1024 + n0 + tx];
    __syncthreads();
#pragma unroll
    for (int q = 0; q < 4; ++q)
        out[(long long)(n0 + ty + 8 * q) * 1024 + k0 + tx] = f2bf(t[tx][ty + 8 * q]);
}

// ---------------- B^T GEMM: C[m][n] = sum_k A[m][k]*B[n][k]  (A,B bf16, acc f32) -------
// OUT_MODE: 0 = bf16 out, 1 = f32 out.  BIAS_MODE: 0 none, 1 bias[n], 2 bias[m].
#define BM 128
#define BN 128
#define BKT 64

template<int OUT_MODE, int BIAS_MODE>
__global__ __launch_bounds__(256) void gemm_bt(
    const unsigned short* __restrict__ A, int lda, long long strideA,
    const unsigned short* __restrict__ B, int ldb, long long strideB,
    void* __restrict__ Cv, int ldc, long long strideC,
    const float* __restrict__ bias, int K, float scale)
{
    int bz = blockIdx.z;
    A += (long long)bz * strideA;
    B += (long long)bz * strideB;
    int m0 = blockIdx.y * BM, n0 = blockIdx.x * BN;

    __shared__ __align__(16) unsigned short As[BM * BKT];
    __shared__ __align__(16) unsigned short Bs[BN * BKT];

    int tid  = threadIdx.x;
    int lane = tid & 63, w = tid >> 6;
    int wm = w >> 1, wn = w & 1;          // 2x2 waves over the 128x128 tile

    f32x4 acc[4][4] = {};

    // staging: each wave stages 8 rows (1 KiB) per global_load_lds.
    // LDS is linear [row][slot16]; source slot is XOR-preswizzled so that
    // LDS slot c of row r holds logical slot (c ^ (r&7)).
    int srow  = lane >> 3;                 // 0..7
    int sslot = (lane & 7) ^ srow;         // pre-swizzled 16B slot in global
    const unsigned short* Ab = A + (long long)(m0 + srow) * lda + sslot * 8;
    const unsigned short* Bb = B + (long long)(n0 + srow) * ldb + sslot * 8;

    for (int kt = 0; kt < K; kt += BKT) {
#pragma unroll
        for (int p = 0; p < 4; ++p) {
            int rbase = (p * 4 + w) * 8;   // wave-uniform base row
            __builtin_amdgcn_global_load_lds(
                (const __attribute__((address_space(1))) void*)(Ab + (long long)rbase * lda + kt),
                (__attribute__((address_space(3))) void*)(As + rbase * BKT), 16, 0, 0);
            __builtin_amdgcn_global_load_lds(
                (const __attribute__((address_space(1))) void*)(Bb + (long long)rbase * ldb + kt),
                (__attribute__((address_space(3))) void*)(Bs + rbase * BKT), 16, 0, 0);
        }
        __syncthreads();
#pragma unroll
        for (int s = 0; s < 2; ++s) {
            int kslot = s * 4 + (lane >> 4);        // logical 16B k-slot 0..7
            bf16x8 af[4], bf[4];
#pragma unroll
            for (int i = 0; i < 4; ++i) {
                int ar = wm * 64 + i * 16 + (lane & 15);
                af[i] = *(const bf16x8*)(As + ar * BKT + ((kslot ^ (ar & 7)) * 8));
                int br = wn * 64 + i * 16 + (lane & 15);
                bf[i] = *(const bf16x8*)(Bs + br * BKT + ((kslot ^ (br & 7)) * 8));
            }
#pragma unroll
            for (int i = 0; i < 4; ++i)
#pragma unroll
                for (int j = 0; j < 4; ++j)
                    acc[i][j] = __builtin_amdgcn_mfma_f32_16x16x32_bf16(af[i], bf[j], acc[i][j], 0, 0, 0);
        }
        __syncthreads();
    }

    // epilogue: D frag layout col = lane&15 (N), row = (lane>>4)*4 + r (M)
    unsigned short* Cb = (unsigned short*)Cv;
    float* Cf = (float*)Cv;
    long long cbase = (long long)bz * strideC;
#pragma unroll
    for (int i = 0; i < 4; ++i) {
#pragma unroll
        for (int j = 0; j < 4; ++j) {
            int n = n0 + wn * 64 + j * 16 + (lane & 15);
            float bn = (BIAS_MODE == 1) ? bias[n] : 0.0f;
#pragma unroll
            for (int r = 0; r < 4; ++r) {
                int m = m0 + wm * 64 + i * 16 + ((lane >> 4) << 2) + r;
                float v = acc[i][j][r] * scale + bn;
                if (BIAS_MODE == 2) v += bias[m];
                long long idx = cbase + (long long)m * ldc + n;
                if (OUT_MODE == 0) Cb[idx] = f2bf(v);
                else               Cf[idx] = v;
            }
        }
    }
}

// ------- row softmax over bf16 scores, in place: S[row][2048] bf16 -> P bf16 -------
__global__ __launch_bounds__(256) void softmax_rows_bf16(unsigned short* __restrict__ S) {
    int row  = blockIdx.x * 4 + (threadIdx.x >> 6);
    int lane = threadIdx.x & 63;
    unsigned short* Srow = S + (long long)row * 2048;
    float v[32];
    float mx = -1e30f;
#pragma unroll
    for (int j = 0; j < 4; ++j) {
        bf16x8 h = *(const bf16x8*)(Srow + j * 512 + lane * 8);
#pragma unroll
        for (int e = 0; e < 8; ++e) {
            float f = bf2f((unsigned short)h[e]);
            v[j * 8 + e] = f;
            mx = fmaxf(mx, f);
        }
    }
#pragma unroll
    for (int o = 32; o; o >>= 1) mx = fmaxf(mx, __shfl_xor(mx, o));
    float sum = 0.0f;
#pragma unroll
    for (int e = 0; e < 32; ++e) {
        v[e] = __expf(v[e] - mx);
        sum += v[e];
    }
#pragma unroll
    for (int o = 32; o; o >>= 1) sum += __shfl_xor(sum, o);
    float inv = 1.0f / sum;
#pragma unroll
    for (int j = 0; j < 4; ++j) {
        bf16x8 h;
#pragma unroll
        for (int e = 0; e < 8; ++e) h[e] = (short)f2bf(v[j * 8 + e] * inv);
        *(bf16x8*)(Srow + j * 512 + lane * 8) = h;
    }
}

extern "C" void kernel_launch(void* const* d_in, const int* in_sizes, int n_in,
                              void* d_out, int out_size, void* d_ws, size_t ws_size,
                              hipStream_t stream) {
    (void)in_sizes; (void)n_in; (void)out_size; (void)ws_size;
    const float* x  = (const float*)d_in[0];
    const float* Wq = (const float*)d_in[1];
    const float* bq = (const float*)d_in[2];
    const float* Wk = (const float*)d_in[3];
    const float* bk = (const float*)d_in[4];
    const float* Wv = (const float*)d_in[5];
    const float* bv = (const float*)d_in[6];

    const long long M  = 8LL * 2048;       // 16384 rows
    const long long D  = 1024;
    const long long S  = 2048;

    // workspace layout (bytes) — peak 174,063,616 B (~166 MiB)
    char* ws = (char*)d_ws;
    unsigned short* Wt  = (unsigned short*)ws;                       //   6,291,456 B (q,k,v)
    unsigned short* Qb  = (unsigned short*)(ws + 6291456);           //  33,554,432
    unsigned short* Kb  = (unsigned short*)(ws + 39845888);          //  33,554,432
    unsigned short* Vt  = (unsigned short*)(ws + 73400320);          //  33,554,432
    unsigned short* xb  = (unsigned short*)(ws + 106954752);         //  33,554,432 (dead after V proj)
    unsigned short* Sb  = (unsigned short*)(ws + 106954752);         //  67,108,864 (bf16 scores, overlays xb)

    // 1) convert x -> bf16
    cvt_f32_bf16<<<dim3(16384), dim3(256), 0, stream>>>(x, xb);
    // 2) W^T -> bf16 (3 mats)
    transpose_w<<<dim3(32, 32, 3), dim3(32, 8), 0, stream>>>(Wq, Wk, Wv, Wt);

    // 3) Q = xb @ Wq + bq   -> bf16 [16384][1024]
    gemm_bt<0, 1><<<dim3(D / BN, M / BM, 1), dim3(256), 0, stream>>>(
        xb, 1024, 0, Wt, 1024, 0, Qb, 1024, 0, bq, 1024, 1.0f);
    // 4) K
    gemm_bt<0, 1><<<dim3(D / BN, M / BM, 1), dim3(256), 0, stream>>>(
        xb, 1024, 0, Wt + 1048576, 1024, 0, Kb, 1024, 0, bk, 1024, 1.0f);
    // 5) Vt[d][m] = sum_k Wvt[d][k] xb[m][k] + bv[d]  -> bf16 [1024][16384]
    gemm_bt<0, 2><<<dim3(M / BN, D / BM, 1), dim3(256), 0, stream>>>(
        Wt + 2097152, 1024, 0, xb, 1024, 0, Vt, 16384, 0, bv, 1024, 1.0f);

    // 6) scores: S[b][q][kv] = (Q @ K^T) * 1/32   -> bf16 (xb is dead now)
    gemm_bt<0, 0><<<dim3(S / BN, S / BM, 8), dim3(256), 0, stream>>>(
        Qb, 1024, 2097152LL, Kb, 1024, 2097152LL,
        Sb, 2048, 4194304LL, nullptr, 1024, 0.03125f);

    // 7) softmax rows in place (bf16 -> bf16)
    softmax_rows_bf16<<<dim3(4096), dim3(256), 0, stream>>>(Sb);

    // 8) out[b][q][d] = P @ V = sum_kv P[q][kv] * Vt[d][b*2048+kv]
    gemm_bt<1, 0><<<dim3(D / BN, S / BM, 8), dim3(256), 0, stream>>>(
        Sb, 2048, 4194304LL,
        Vt, 16384, 2048LL,
        d_out, 1024, 2097152LL, nullptr, 2048, 1.0f);
}

// Round 3
// 340.205 us; speedup vs baseline: 1.1005x; 1.1005x over previous
//
#include <hip/hip_runtime.h>

typedef __attribute__((ext_vector_type(4))) float f32x4;
typedef __attribute__((ext_vector_type(8))) short bf16x8;
typedef __attribute__((ext_vector_type(4))) unsigned short u16x4;

static __device__ __forceinline__ unsigned short f2bf(float f) {
    union { float f; unsigned int u; } a; a.f = f;
    unsigned int u = a.u;
    unsigned int r = (u + 0x7FFFu + ((u >> 16) & 1u)) >> 16;
    return (unsigned short)r;
}
static __device__ __forceinline__ float bf2f(unsigned short h) {
    union { unsigned int u; float f; } a; a.u = ((unsigned int)h) << 16;
    return a.f;
}

// ---------------- convert x (fp32 -> bf16), vectorized ----------------
__global__ __launch_bounds__(256) void cvt_f32_bf16(const float* __restrict__ in,
                                                    unsigned short* __restrict__ out) {
    long long i = ((long long)blockIdx.x * 256 + threadIdx.x) * 4;
    float4 f = *(const float4*)(in + i);
    u16x4 u;
    u[0] = f2bf(f.x); u[1] = f2bf(f.y); u[2] = f2bf(f.z); u[3] = f2bf(f.w);
    *(u16x4*)(out + i) = u;
}

// ---------------- transpose W [1024][1024] f32 -> Wt [1024][1024] bf16 ----------------
__global__ __launch_bounds__(256) void transpose_w(const float* __restrict__ W0,
                                                   const float* __restrict__ W1,
                                                   const float* __restrict__ W2,
                                                   unsigned short* __restrict__ Wt) {
    __shared__ float t[32][33];
    int mat = blockIdx.z;
    const float* W = (mat == 0) ? W0 : (mat == 1) ? W1 : W2;
    unsigned short* out = Wt + (long long)mat * 1024 * 1024;
    int n0 = blockIdx.x * 32, k0 = blockIdx.y * 32;
    int tx = threadIdx.x, ty = threadIdx.y;   // 32 x 8
#pragma unroll
    for (int q = 0; q < 4; ++q)
        t[ty + 8 * q][tx] = W[(long long)(k0 + ty + 8 * q) * 1024 + n0 + tx];
    __syncthreads();
#pragma unroll
    for (int q = 0; q < 4; ++q)
        out[(long long)(n0 + ty + 8 * q) * 1024 + k0 + tx] = f2bf(t[tx][ty + 8 * q]);
}

// ============ 256x256 8-phase B^T GEMM: C[m][n] = sum_k A[m][k]*B[n][k] ============
// 512 threads, 8 waves (2M x 4N), BK=64, double-buffered LDS (128 KiB), counted vmcnt.
// OUT_MODE: 0 = bf16 out, 1 = f32 out.  BIAS_MODE: 0 none, 1 bias[n], 2 bias[m].
#define GBM 256
#define GBN 256
#define GBK 64

template<int OUT_MODE, int BIAS_MODE>
__global__ __launch_bounds__(512, 2) void gemm8p(
    const unsigned short* __restrict__ A, int lda, long long strideA,
    const unsigned short* __restrict__ B, int ldb, long long strideB,
    void* __restrict__ Cv, int ldc, long long strideC,
    const float* __restrict__ bias, int K, float scale)
{
    __shared__ __align__(16) unsigned short As[2][GBM * GBK];
    __shared__ __align__(16) unsigned short Bs[2][GBN * GBK];

    const int bz = blockIdx.z;
    const unsigned short* Ag = A + (long long)bz * strideA;
    const unsigned short* Bg = B + (long long)bz * strideB;
    const int m0 = blockIdx.y * GBM, n0 = blockIdx.x * GBN;

    const int tid  = threadIdx.x;
    const int lane = tid & 63, w = tid >> 6;      // 8 waves
    const int wm = w >> 2, wn = w & 3;            // wave rows: wm*128, cols: wn*64
    const int l15 = lane & 15, l4 = lane >> 4;

    // staging source: per-lane row = base + l*64 + w*8 + (lane>>3), pre-swizzled 16B slot
    const int sg = (lane & 7) ^ ((lane >> 3) & 7);
    const unsigned short* Asrc = Ag + (long long)(m0 + w * 8 + (lane >> 3)) * lda + sg * 8;
    const unsigned short* Bsrc = Bg + (long long)(n0 + w * 8 + (lane >> 3)) * ldb + sg * 8;

    f32x4 acc[8][4] = {};

    auto issueA = [&](int p, int kt, int l) {
        __builtin_amdgcn_global_load_lds(
            (const __attribute__((address_space(1))) void*)(Asrc + (long long)(l * 64) * lda + kt),
            (__attribute__((address_space(3))) void*)(&As[p][(l * 64 + w * 8) * GBK]), 16, 0, 0);
    };
    auto issueB = [&](int p, int kt, int l) {
        __builtin_amdgcn_global_load_lds(
            (const __attribute__((address_space(1))) void*)(Bsrc + (long long)(l * 64) * ldb + kt),
            (__attribute__((address_space(3))) void*)(&Bs[p][(l * 64 + w * 8) * GBK]), 16, 0, 0);
    };
    auto readA = [&](bf16x8 (&af)[4], int p, int mh, int ks) {
        const unsigned short* Asp = &As[p][0];
#pragma unroll
        for (int fi = 0; fi < 4; ++fi) {
            int ar = wm * 128 + mh * 64 + fi * 16 + l15;
            int slot = (ks * 4 + l4) ^ (ar & 7);
            af[fi] = *(const bf16x8*)(Asp + ar * GBK + slot * 8);
        }
    };
    auto readB = [&](bf16x8 (&bf)[4], int p, int ks) {
        const unsigned short* Bsp = &Bs[p][0];
#pragma unroll
        for (int nj = 0; nj < 4; ++nj) {
            int br = wn * 64 + nj * 16 + l15;
            int slot = (ks * 4 + l4) ^ (br & 7);
            bf[nj] = *(const bf16x8*)(Bsp + br * GBK + slot * 8);
        }
    };
    auto mfma16 = [&](int mh, bf16x8 (&af)[4], bf16x8 (&bf)[4]) {
#pragma unroll
        for (int fi = 0; fi < 4; ++fi)
#pragma unroll
            for (int nj = 0; nj < 4; ++nj)
                acc[mh * 4 + fi][nj] = __builtin_amdgcn_mfma_f32_16x16x32_bf16(
                    af[fi], bf[nj], acc[mh * 4 + fi][nj], 0, 0, 0);
    };

#define VMCNT2 asm volatile("s_waitcnt vmcnt(2)" ::: "memory")
#define VMCNT0 asm volatile("s_waitcnt vmcnt(0)" ::: "memory")
#define LGKM0  asm volatile("s_waitcnt lgkmcnt(0)" ::: "memory")
#define SCHED0 __builtin_amdgcn_sched_barrier(0)
#define BARR   __builtin_amdgcn_s_barrier()
#define PRIO1  __builtin_amdgcn_s_setprio(1)
#define PRIO0  __builtin_amdgcn_s_setprio(0)

    // prologue: stage tile 0 into buf 0.  Issue order: B0,B1,B2,B3,A0,A2,A1,A3
    issueB(0, 0, 0); issueB(0, 0, 1); issueB(0, 0, 2); issueB(0, 0, 3);
    issueA(0, 0, 0); issueA(0, 0, 2); issueA(0, 0, 1); issueA(0, 0, 3);

    const int NT = K >> 6;
    bf16x8 a0[4], a1[4], b0[4], b1[4];

    for (int t = 0; t < NT - 1; ++t) {
        const int p = t & 1, q = p ^ 1;
        const int kn = (t + 1) << 6;
        // tile entry: need B(all) + A portions 0,2 of tile t  -> 6 oldest of 8
        VMCNT2; BARR;
        // P1: quadrant (mh=0, ks=0)
        issueB(q, kn, 0); issueB(q, kn, 1);
        readA(a0, p, 0, 0); readB(b0, p, 0);
        LGKM0; SCHED0; PRIO1; mfma16(0, a0, b0); PRIO0;
        // need A portions 1,3 of tile t (2 oldest of 4 outstanding)
        VMCNT2; BARR;
        // P2: (mh=1, ks=0)
        issueB(q, kn, 2); issueB(q, kn, 3);
        readA(a1, p, 1, 0);
        LGKM0; SCHED0; PRIO1; mfma16(1, a1, b0); PRIO0;
        // P3: (mh=0, ks=1) — data already guaranteed
        issueA(q, kn, 0); issueA(q, kn, 2);
        readA(a0, p, 0, 1); readB(b1, p, 1);
        LGKM0; SCHED0; PRIO1; mfma16(0, a0, b1); PRIO0;
        // P4: (mh=1, ks=1)
        issueA(q, kn, 1); issueA(q, kn, 3);
        readA(a1, p, 1, 1);
        LGKM0; SCHED0; PRIO1; mfma16(1, a1, b1); PRIO0;
    }
    // last tile: no staging, drain everything
    {
        const int p = (NT - 1) & 1;
        VMCNT0; BARR;
        readA(a0, p, 0, 0); readB(b0, p, 0);
        LGKM0; SCHED0; PRIO1; mfma16(0, a0, b0); PRIO0;
        readA(a1, p, 1, 0);
        LGKM0; SCHED0; PRIO1; mfma16(1, a1, b0); PRIO0;
        readA(a0, p, 0, 1); readB(b1, p, 1);
        LGKM0; SCHED0; PRIO1; mfma16(0, a0, b1); PRIO0;
        readA(a1, p, 1, 1);
        LGKM0; SCHED0; PRIO1; mfma16(1, a1, b1); PRIO0;
    }

    // epilogue: C/D frag layout col = lane&15 (N), row = (lane>>4)*4 + r (M)
    const float* bias_v = bias;
    asm volatile("" : "+s"(bias_v));   // keep bias loads out of the vmcnt-counted loop
    unsigned short* Cb = (unsigned short*)Cv;
    float* Cf = (float*)Cv;
    long long cbase = (long long)bz * strideC;
#pragma unroll
    for (int mh = 0; mh < 2; ++mh)
#pragma unroll
    for (int fi = 0; fi < 4; ++fi) {
#pragma unroll
        for (int nj = 0; nj < 4; ++nj) {
            int n = n0 + wn * 64 + nj * 16 + l15;
            float bn = (BIAS_MODE == 1) ? bias_v[n] : 0.0f;
#pragma unroll
            for (int r = 0; r < 4; ++r) {
                int m = m0 + wm * 128 + mh * 64 + fi * 16 + l4 * 4 + r;
                float v = acc[mh * 4 + fi][nj][r] * scale + bn;
                if (BIAS_MODE == 2) v += bias_v[m];
                long long idx = cbase + (long long)m * ldc + n;
                if (OUT_MODE == 0) Cb[idx] = f2bf(v);
                else               Cf[idx] = v;
            }
        }
    }
}

// ------- row softmax over bf16 scores, in place: S[row][2048] bf16 -> P bf16 -------
__global__ __launch_bounds__(256) void softmax_rows_bf16(unsigned short* __restrict__ S) {
    int row  = blockIdx.x * 4 + (threadIdx.x >> 6);
    int lane = threadIdx.x & 63;
    unsigned short* Srow = S + (long long)row * 2048;
    float v[32];
    float mx = -1e30f;
#pragma unroll
    for (int j = 0; j < 4; ++j) {
        bf16x8 h = *(const bf16x8*)(Srow + j * 512 + lane * 8);
#pragma unroll
        for (int e = 0; e < 8; ++e) {
            float f = bf2f((unsigned short)h[e]);
            v[j * 8 + e] = f;
            mx = fmaxf(mx, f);
        }
    }
#pragma unroll
    for (int o = 32; o; o >>= 1) mx = fmaxf(mx, __shfl_xor(mx, o));
    float sum = 0.0f;
#pragma unroll
    for (int e = 0; e < 32; ++e) {
        v[e] = __expf(v[e] - mx);
        sum += v[e];
    }
#pragma unroll
    for (int o = 32; o; o >>= 1) sum += __shfl_xor(sum, o);
    float inv = 1.0f / sum;
#pragma unroll
    for (int j = 0; j < 4; ++j) {
        bf16x8 h;
#pragma unroll
        for (int e = 0; e < 8; ++e) h[e] = (short)f2bf(v[j * 8 + e] * inv);
        *(bf16x8*)(Srow + j * 512 + lane * 8) = h;
    }
}

extern "C" void kernel_launch(void* const* d_in, const int* in_sizes, int n_in,
                              void* d_out, int out_size, void* d_ws, size_t ws_size,
                              hipStream_t stream) {
    (void)in_sizes; (void)n_in; (void)out_size; (void)ws_size;
    const float* x  = (const float*)d_in[0];
    const float* Wq = (const float*)d_in[1];
    const float* bq = (const float*)d_in[2];
    const float* Wk = (const float*)d_in[3];
    const float* bk = (const float*)d_in[4];
    const float* Wv = (const float*)d_in[5];
    const float* bv = (const float*)d_in[6];

    // workspace layout (bytes) — peak ~166 MiB
    char* ws = (char*)d_ws;
    unsigned short* Wt  = (unsigned short*)ws;                       //   6,291,456 B (q,k,v)
    unsigned short* Qb  = (unsigned short*)(ws + 6291456);           //  33,554,432
    unsigned short* Kb  = (unsigned short*)(ws + 39845888);          //  33,554,432
    unsigned short* Vt  = (unsigned short*)(ws + 73400320);          //  33,554,432
    unsigned short* xb  = (unsigned short*)(ws + 106954752);         //  33,554,432 (dead after V proj)
    unsigned short* Sb  = (unsigned short*)(ws + 106954752);         //  67,108,864 (bf16 scores, overlays xb)

    // 1) convert x -> bf16
    cvt_f32_bf16<<<dim3(16384), dim3(256), 0, stream>>>(x, xb);
    // 2) W^T -> bf16 (3 mats)
    transpose_w<<<dim3(32, 32, 3), dim3(32, 8), 0, stream>>>(Wq, Wk, Wv, Wt);

    // 3) Q = xb @ Wq + bq   -> bf16 [16384][1024]
    gemm8p<0, 1><<<dim3(4, 64, 1), dim3(512), 0, stream>>>(
        xb, 1024, 0, Wt, 1024, 0, Qb, 1024, 0, bq, 1024, 1.0f);
    // 4) K
    gemm8p<0, 1><<<dim3(4, 64, 1), dim3(512), 0, stream>>>(
        xb, 1024, 0, Wt + 1048576, 1024, 0, Kb, 1024, 0, bk, 1024, 1.0f);
    // 5) Vt[d][m] = sum_k Wvt[d][k] xb[m][k] + bv[d]  -> bf16 [1024][16384]
    gemm8p<0, 2><<<dim3(64, 4, 1), dim3(512), 0, stream>>>(
        Wt + 2097152, 1024, 0, xb, 1024, 0, Vt, 16384, 0, bv, 1024, 1.0f);

    // 6) scores: S[b][q][kv] = (Q @ K^T) * 1/32   -> bf16 (xb dead now)
    gemm8p<0, 0><<<dim3(8, 8, 8), dim3(512), 0, stream>>>(
        Qb, 1024, 2097152LL, Kb, 1024, 2097152LL,
        Sb, 2048, 4194304LL, nullptr, 1024, 0.03125f);

    // 7) softmax rows in place (bf16 -> bf16)
    softmax_rows_bf16<<<dim3(4096), dim3(256), 0, stream>>>(Sb);

    // 8) out[b][q][d] = P @ V = sum_kv P[q][kv] * Vt[d][b*2048+kv]
    gemm8p<1, 0><<<dim3(4, 8, 8), dim3(512), 0, stream>>>(
        Sb, 2048, 4194304LL,
        Vt, 16384, 2048LL,
        d_out, 1024, 2097152LL, nullptr, 2048, 1.0f);
}

// Round 4
// 269.687 us; speedup vs baseline: 1.3882x; 1.2615x over previous
//
#include <hip/hip_runtime.h>

typedef __attribute__((ext_vector_type(4))) float f32x4;
typedef __attribute__((ext_vector_type(8))) short bf16x8;
typedef __attribute__((ext_vector_type(4))) unsigned short u16x4;

static __device__ __forceinline__ unsigned short f2bf(float f) {
    union { float f; unsigned int u; } a; a.f = f;
    unsigned int u = a.u;
    unsigned int r = (u + 0x7FFFu + ((u >> 16) & 1u)) >> 16;
    return (unsigned short)r;
}
static __device__ __forceinline__ float bf2f(unsigned short h) {
    union { unsigned int u; float f; } a; a.u = ((unsigned int)h) << 16;
    return a.f;
}
static __device__ __forceinline__ unsigned lds_off(const void* p) {
    return (unsigned)(unsigned long long)(const __attribute__((address_space(3))) void*)p;
}

// ---------------- convert x (fp32 -> bf16), vectorized ----------------
__global__ __launch_bounds__(256) void cvt_f32_bf16(const float* __restrict__ in,
                                                    unsigned short* __restrict__ out) {
    long long i = ((long long)blockIdx.x * 256 + threadIdx.x) * 4;
    float4 f = *(const float4*)(in + i);
    u16x4 u;
    u[0] = f2bf(f.x); u[1] = f2bf(f.y); u[2] = f2bf(f.z); u[3] = f2bf(f.w);
    *(u16x4*)(out + i) = u;
}

// ---------------- transpose W [1024][1024] f32 -> Wt [1024][1024] bf16 ----------------
__global__ __launch_bounds__(256) void transpose_w(const float* __restrict__ W0,
                                                   const float* __restrict__ W1,
                                                   const float* __restrict__ W2,
                                                   unsigned short* __restrict__ Wt) {
    __shared__ float t[32][33];
    int mat = blockIdx.z;
    const float* W = (mat == 0) ? W0 : (mat == 1) ? W1 : W2;
    unsigned short* out = Wt + (long long)mat * 1024 * 1024;
    int n0 = blockIdx.x * 32, k0 = blockIdx.y * 32;
    int tx = threadIdx.x, ty = threadIdx.y;   // 32 x 8
#pragma unroll
    for (int q = 0; q < 4; ++q)
        t[ty + 8 * q][tx] = W[(long long)(k0 + ty + 8 * q) * 1024 + n0 + tx];
    __syncthreads();
#pragma unroll
    for (int q = 0; q < 4; ++q)
        out[(long long)(n0 + ty + 8 * q) * 1024 + k0 + tx] = f2bf(t[tx][ty + 8 * q]);
}

// ============ 256x256 8-phase B^T GEMM: C[m][n] = sum_k A[m][k]*B[n][k] ============
// 512 threads, 8 waves (2M x 4N), BK=64, double-buffered LDS (128 KiB), counted vmcnt,
// inline-asm ds_read_b128 (compiler-invisible LDS reads -> no auto vmcnt(0) drains).
// OUT_MODE: 0 = bf16 out, 1 = f32 out.  BIAS_MODE: 0 none, 1 bias[n], 2 bias[m].
#define GBM 256
#define GBN 256
#define GBK 64

template<int OUT_MODE, int BIAS_MODE>
__global__ __launch_bounds__(512, 2) void gemm8p(
    const unsigned short* __restrict__ A, int lda, long long strideA,
    const unsigned short* __restrict__ B, int ldb, long long strideB,
    void* __restrict__ Cv, int ldc, long long strideC,
    const float* __restrict__ bias, int K, float scale)
{
    __shared__ __align__(16) unsigned short As[2][GBM * GBK];
    __shared__ __align__(16) unsigned short Bs[2][GBN * GBK];

    // ---- bijective XCD swizzle (all grids here have nwg % 8 == 0) ----
    const int gx = gridDim.x, gy = gridDim.y;
    int lin = blockIdx.x + gx * (blockIdx.y + gy * blockIdx.z);
    const int nwg = gx * gy * gridDim.z;
    const int qch = nwg >> 3;
    int swz = (lin & 7) * qch + (lin >> 3);
    const int bx = swz % gx; int t2 = swz / gx;
    const int by = t2 % gy;  const int bz = t2 / gy;

    const unsigned short* Ag = A + (long long)bz * strideA;
    const unsigned short* Bg = B + (long long)bz * strideB;
    const int m0 = by * GBM, n0 = bx * GBN;

    const int tid  = threadIdx.x;
    const int lane = tid & 63, w = tid >> 6;      // 8 waves
    const int wm = w >> 2, wn = w & 3;            // wave rows: wm*128, cols: wn*64
    const int l15 = lane & 15, l4 = lane >> 4;

    // staging source: per-lane row = base + l*64 + w*8 + (lane>>3), pre-swizzled 16B slot
    const int sg = (lane & 7) ^ ((lane >> 3) & 7);
    const unsigned short* Asrc = Ag + (long long)(m0 + w * 8 + (lane >> 3)) * lda + sg * 8;
    const unsigned short* Bsrc = Bg + (long long)(n0 + w * 8 + (lane >> 3)) * ldb + sg * 8;

    f32x4 acc[8][4] = {};

    auto issueA = [&](int p, int kt, int l) {
        __builtin_amdgcn_global_load_lds(
            (const __attribute__((address_space(1))) void*)(Asrc + (long long)(l * 64) * lda + kt),
            (__attribute__((address_space(3))) void*)(&As[p][(l * 64 + w * 8) * GBK]), 16, 0, 0);
    };
    auto issueB = [&](int p, int kt, int l) {
        __builtin_amdgcn_global_load_lds(
            (const __attribute__((address_space(1))) void*)(Bsrc + (long long)(l * 64) * ldb + kt),
            (__attribute__((address_space(3))) void*)(&Bs[p][(l * 64 + w * 8) * GBK]), 16, 0, 0);
    };
    auto readA = [&](bf16x8 (&af)[4], int p, int mh, int ks) {
#pragma unroll
        for (int fi = 0; fi < 4; ++fi) {
            int ar = wm * 128 + mh * 64 + fi * 16 + l15;
            int slot = (ks * 4 + l4) ^ (ar & 7);
            unsigned off = lds_off(&As[p][ar * GBK + slot * 8]);
            asm volatile("ds_read_b128 %0, %1" : "=v"(af[fi]) : "v"(off));
        }
    };
    auto readB = [&](bf16x8 (&bf)[4], int p, int ks) {
#pragma unroll
        for (int nj = 0; nj < 4; ++nj) {
            int br = wn * 64 + nj * 16 + l15;
            int slot = (ks * 4 + l4) ^ (br & 7);
            unsigned off = lds_off(&Bs[p][br * GBK + slot * 8]);
            asm volatile("ds_read_b128 %0, %1" : "=v"(bf[nj]) : "v"(off));
        }
    };
    auto mfma16 = [&](int mh, bf16x8 (&af)[4], bf16x8 (&bf)[4]) {
#pragma unroll
        for (int fi = 0; fi < 4; ++fi)
#pragma unroll
            for (int nj = 0; nj < 4; ++nj)
                acc[mh * 4 + fi][nj] = __builtin_amdgcn_mfma_f32_16x16x32_bf16(
                    af[fi], bf[nj], acc[mh * 4 + fi][nj], 0, 0, 0);
    };

#define VMCNT2 asm volatile("s_waitcnt vmcnt(2)" ::: "memory")
#define VMCNT0 asm volatile("s_waitcnt vmcnt(0)" ::: "memory")
#define LGKM0  asm volatile("s_waitcnt lgkmcnt(0)" ::: "memory")
#define SCHED0 __builtin_amdgcn_sched_barrier(0)
#define BARR   __builtin_amdgcn_s_barrier()
#define PRIO1  __builtin_amdgcn_s_setprio(1)
#define PRIO0  __builtin_amdgcn_s_setprio(0)

    // prologue: stage tile 0 into buf 0.  Issue order: B0,B1,B2,B3,A0,A2,A1,A3
    issueB(0, 0, 0); issueB(0, 0, 1); issueB(0, 0, 2); issueB(0, 0, 3);
    issueA(0, 0, 0); issueA(0, 0, 2); issueA(0, 0, 1); issueA(0, 0, 3);

    const int NT = K >> 6;
    bf16x8 a0[4], a1[4], b0[4], b1[4];

    for (int t = 0; t < NT - 1; ++t) {
        const int p = t & 1, q = p ^ 1;
        const int kn = (t + 1) << 6;
        // tile entry: need B(all) + A segments 0,2 of tile t -> 6 oldest of 8 done
        VMCNT2; BARR; SCHED0;
        // P1: quadrant (mh=0, ks=0)
        issueB(q, kn, 0); issueB(q, kn, 1);
        readA(a0, p, 0, 0); readB(b0, p, 0);
        LGKM0; SCHED0; PRIO1; mfma16(0, a0, b0); PRIO0;
        // need A segments 1,3 of tile t (its 2 remaining oldest)
        VMCNT2; BARR; SCHED0;
        // P2: (mh=1, ks=0)
        issueB(q, kn, 2); issueB(q, kn, 3);
        readA(a1, p, 1, 0);
        LGKM0; SCHED0; PRIO1; mfma16(1, a1, b0); PRIO0;
        // P3: (mh=0, ks=1) — data already guaranteed
        issueA(q, kn, 0); issueA(q, kn, 2);
        readA(a0, p, 0, 1); readB(b1, p, 1);
        LGKM0; SCHED0; PRIO1; mfma16(0, a0, b1); PRIO0;
        // P4: (mh=1, ks=1)
        issueA(q, kn, 1); issueA(q, kn, 3);
        readA(a1, p, 1, 1);
        LGKM0; SCHED0; PRIO1; mfma16(1, a1, b1); PRIO0;
    }
    // last tile: no staging, drain everything
    {
        const int p = (NT - 1) & 1;
        VMCNT0; BARR; SCHED0;
        readA(a0, p, 0, 0); readB(b0, p, 0);
        LGKM0; SCHED0; PRIO1; mfma16(0, a0, b0); PRIO0;
        readA(a1, p, 1, 0);
        LGKM0; SCHED0; PRIO1; mfma16(1, a1, b0); PRIO0;
        readA(a0, p, 0, 1); readB(b1, p, 1);
        LGKM0; SCHED0; PRIO1; mfma16(0, a0, b1); PRIO0;
        readA(a1, p, 1, 1);
        LGKM0; SCHED0; PRIO1; mfma16(1, a1, b1); PRIO0;
    }

    // epilogue: C/D frag layout col = lane&15 (N), row = (lane>>4)*4 + r (M)
    const float* bias_v = bias;
    asm volatile("" : "+s"(bias_v));   // keep bias loads out of the vmcnt-counted loop
    unsigned short* Cb = (unsigned short*)Cv;
    float* Cf = (float*)Cv;
    long long cbase = (long long)bz * strideC;
#pragma unroll
    for (int mh = 0; mh < 2; ++mh)
#pragma unroll
    for (int fi = 0; fi < 4; ++fi) {
#pragma unroll
        for (int nj = 0; nj < 4; ++nj) {
            int n = n0 + wn * 64 + nj * 16 + l15;
            float bn = (BIAS_MODE == 1) ? bias_v[n] : 0.0f;
#pragma unroll
            for (int r = 0; r < 4; ++r) {
                int m = m0 + wm * 128 + mh * 64 + fi * 16 + l4 * 4 + r;
                float v = acc[mh * 4 + fi][nj][r] * scale + bn;
                if (BIAS_MODE == 2) v += bias_v[m];
                long long idx = cbase + (long long)m * ldc + n;
                if (OUT_MODE == 0) Cb[idx] = f2bf(v);
                else               Cf[idx] = v;
            }
        }
    }
}

// ------- row softmax over bf16 scores, in place: S[row][2048] bf16 -> P bf16 -------
__global__ __launch_bounds__(256) void softmax_rows_bf16(unsigned short* __restrict__ S) {
    int row  = blockIdx.x * 4 + (threadIdx.x >> 6);
    int lane = threadIdx.x & 63;
    unsigned short* Srow = S + (long long)row * 2048;
    float v[32];
    float mx = -1e30f;
#pragma unroll
    for (int j = 0; j < 4; ++j) {
        bf16x8 h = *(const bf16x8*)(Srow + j * 512 + lane * 8);
#pragma unroll
        for (int e = 0; e < 8; ++e) {
            float f = bf2f((unsigned short)h[e]);
            v[j * 8 + e] = f;
            mx = fmaxf(mx, f);
        }
    }
#pragma unroll
    for (int o = 32; o; o >>= 1) mx = fmaxf(mx, __shfl_xor(mx, o));
    float sum = 0.0f;
#pragma unroll
    for (int e = 0; e < 32; ++e) {
        v[e] = __expf(v[e] - mx);
        sum += v[e];
    }
#pragma unroll
    for (int o = 32; o; o >>= 1) sum += __shfl_xor(sum, o);
    float inv = 1.0f / sum;
#pragma unroll
    for (int j = 0; j < 4; ++j) {
        bf16x8 h;
#pragma unroll
        for (int e = 0; e < 8; ++e) h[e] = (short)f2bf(v[j * 8 + e] * inv);
        *(bf16x8*)(Srow + j * 512 + lane * 8) = h;
    }
}

extern "C" void kernel_launch(void* const* d_in, const int* in_sizes, int n_in,
                              void* d_out, int out_size, void* d_ws, size_t ws_size,
                              hipStream_t stream) {
    (void)in_sizes; (void)n_in; (void)out_size; (void)ws_size;
    const float* x  = (const float*)d_in[0];
    const float* Wq = (const float*)d_in[1];
    const float* bq = (const float*)d_in[2];
    const float* Wk = (const float*)d_in[3];
    const float* bk = (const float*)d_in[4];
    const float* Wv = (const float*)d_in[5];
    const float* bv = (const float*)d_in[6];

    // workspace layout (bytes) — peak ~166 MiB
    char* ws = (char*)d_ws;
    unsigned short* Wt  = (unsigned short*)ws;                       //   6,291,456 B (q,k,v)
    unsigned short* Qb  = (unsigned short*)(ws + 6291456);           //  33,554,432
    unsigned short* Kb  = (unsigned short*)(ws + 39845888);          //  33,554,432
    unsigned short* Vt  = (unsigned short*)(ws + 73400320);          //  33,554,432
    unsigned short* xb  = (unsigned short*)(ws + 106954752);         //  33,554,432 (dead after V proj)
    unsigned short* Sb  = (unsigned short*)(ws + 106954752);         //  67,108,864 (bf16 scores, overlays xb)

    // 1) convert x -> bf16
    cvt_f32_bf16<<<dim3(16384), dim3(256), 0, stream>>>(x, xb);
    // 2) W^T -> bf16 (3 mats)
    transpose_w<<<dim3(32, 32, 3), dim3(32, 8), 0, stream>>>(Wq, Wk, Wv, Wt);

    // 3) Q = xb @ Wq + bq   -> bf16 [16384][1024]
    gemm8p<0, 1><<<dim3(4, 64, 1), dim3(512), 0, stream>>>(
        xb, 1024, 0, Wt, 1024, 0, Qb, 1024, 0, bq, 1024, 1.0f);
    // 4) K
    gemm8p<0, 1><<<dim3(4, 64, 1), dim3(512), 0, stream>>>(
        xb, 1024, 0, Wt + 1048576, 1024, 0, Kb, 1024, 0, bk, 1024, 1.0f);
    // 5) Vt[d][m] = sum_k Wvt[d][k] xb[m][k] + bv[d]  -> bf16 [1024][16384]
    gemm8p<0, 2><<<dim3(64, 4, 1), dim3(512), 0, stream>>>(
        Wt + 2097152, 1024, 0, xb, 1024, 0, Vt, 16384, 0, bv, 1024, 1.0f);

    // 6) scores: S[b][q][kv] = (Q @ K^T) * 1/32   -> bf16 (xb dead now)
    gemm8p<0, 0><<<dim3(8, 8, 8), dim3(512), 0, stream>>>(
        Qb, 1024, 2097152LL, Kb, 1024, 2097152LL,
        Sb, 2048, 4194304LL, nullptr, 1024, 0.03125f);

    // 7) softmax rows in place (bf16 -> bf16)
    softmax_rows_bf16<<<dim3(4096), dim3(256), 0, stream>>>(Sb);

    // 8) out[b][q][d] = P @ V = sum_kv P[q][kv] * Vt[d][b*2048+kv]
    gemm8p<1, 0><<<dim3(4, 8, 8), dim3(512), 0, stream>>>(
        Sb, 2048, 4194304LL,
        Vt, 16384, 2048LL,
        d_out, 1024, 2097152LL, nullptr, 2048, 1.0f);
}